// Round 9
// baseline (94.420 us; speedup 1.0000x reference)
//
#include <hip/hip_runtime.h>
#include <cfloat>

// Problem constants (match reference setup_inputs)
#define BB 4
#define NQ 8192
#define NK 2048
#define CC 128
#define C4 (CC / 4)            // 32 float4 per feature row

#define QPB 64                 // queries per block
#define SPLITS 16              // key splits
#define KPS (NK / SPLITS)      // 128 keys per split
#define KPAD 2                 // split stride 2080 B: wave's 4 splits hit
                               // disjoint bank quads (R7 conflict fix)
#define KROW (KPS + KPAD)      // 130
#define QPT 4                  // queries per thread
#define NTHR (QPB * SPLITS / QPT)   // 256 threads
#define RD_ROW 68              // 64 u32 + 4 pad

typedef float v2f __attribute__((ext_vector_type(2)));

static __device__ __forceinline__ float fmed3(float a, float b, float c) {
    return __builtin_amdgcn_fmed3f(a, b, c);
}

// ---------------------------------------------------------------------------
// Kernel A: kNN select — staging direct from xyz_k (pack fused: kills the
// pack_keys launch + keys ws round-trip), scan + merge + fp64 refine, then
// writes per-query {weights, indices} to ws. No vk access (cold-gather work
// moved to kernel B where TLP can hide it).
//   grid = (NQ/QPB, BB) = 512, block = 256
// ---------------------------------------------------------------------------
__global__ __launch_bounds__(NTHR, 2) void fp_knn(
    const float*  __restrict__ xyz_q,
    const float*  __restrict__ xyz_k,
    float4*       __restrict__ wsw,     // [BB*NQ] {w0,w1,w2,-}
    int4*         __restrict__ wsi)     // [BB*NQ] {j0,j1,j2,-}
{
    __shared__ float4  ks[SPLITS * KROW];   // 33.3 KiB, bank-staggered splits
    __shared__ unsigned rd[QPB][RD_ROW];    // 17 KiB: packed (dist|global idx)

    const int b     = blockIdx.y;
    const int qbase = blockIdx.x * QPB;
    const int tid   = threadIdx.x;
    const int split = tid >> 4;             // 16 threads per split
    const int g     = tid & 15;             // query group: g, g+16, g+32, g+48

    // ---- stage keys from xyz_k, computing |k|^2 in-flight (== pack_keys) ----
    {
        const float* kb = xyz_k + (size_t)b * NK * 3;
        #pragma unroll
        for (int i = tid; i < NK; i += NTHR) {
            float x = kb[i * 3 + 0];
            float y = kb[i * 3 + 1];
            float z = kb[i * 3 + 2];
            ks[(i >> 7) * KROW + (i & (KPS - 1))] =
                make_float4(x, y, z, fmaf(x, x, fmaf(y, y, z * z)));
        }
    }

    // ---- load 4 queries, rank coefficients packed in query pairs ----
    v2f AX[2], AY[2], AZ[2], QB[2];
    #pragma unroll
    for (int qi = 0; qi < QPT; ++qi) {
        int q = qbase + g + 16 * qi;
        float qx = xyz_q[(b * NQ + q) * 3 + 0];
        float qy = xyz_q[(b * NQ + q) * 3 + 1];
        float qz = xyz_q[(b * NQ + q) * 3 + 2];
        AX[qi >> 1][qi & 1] = -2.0f * qx;
        AY[qi >> 1][qi & 1] = -2.0f * qy;
        AZ[qi >> 1][qi & 1] = -2.0f * qz;
        // t = |q-k|^2 + 1e-3: strictly positive (packed-float order trick valid)
        QB[qi >> 1][qi & 1] = fmaf(qx, qx, fmaf(qy, qy, qz * qz)) + 1.0e-3f;
    }
    __syncthreads();

    const int kbase = split * KROW;         // LDS row base (staggered)
    const int kbeg  = split * KPS;          // global key index base

    // ---- phase 1: scan 128 keys x 4 queries, packed dist + med3 top-4 ----
    float u[QPT][4];
    #pragma unroll
    for (int qi = 0; qi < QPT; ++qi)
        u[qi][0] = u[qi][1] = u[qi][2] = u[qi][3] = FLT_MAX;

    #pragma unroll 8
    for (int j = 0; j < KPS; ++j) {
        float4 kk = ks[kbase + j];
        unsigned kidx = (unsigned)(kbeg + j);
        v2f kx2 = { kk.x, kk.x }, ky2 = { kk.y, kk.y };
        v2f kz2 = { kk.z, kk.z }, kw2 = { kk.w, kk.w };
        #pragma unroll
        for (int pr = 0; pr < 2; ++pr) {
            v2f t2 = __builtin_elementwise_fma(AX[pr], kx2,
                     __builtin_elementwise_fma(AY[pr], ky2,
                     __builtin_elementwise_fma(AZ[pr], kz2, QB[pr]))) + kw2;
            #pragma unroll
            for (int h = 0; h < 2; ++h) {
                int qi = pr * 2 + h;
                float p = __uint_as_float(
                    (__float_as_uint(t2[h]) & 0xFFFFF800u) | kidx);
                u[qi][3] = fmed3(p, u[qi][2], u[qi][3]);
                u[qi][2] = fmed3(p, u[qi][1], u[qi][2]);
                u[qi][1] = fmed3(p, u[qi][0], u[qi][1]);
                u[qi][0] = fminf(u[qi][0], p);
            }
        }
    }

    // ---- write per-(query,split) top-4 as one uint4 each ----
    #pragma unroll
    for (int qi = 0; qi < QPT; ++qi) {
        int ql = g + 16 * qi;
        uint4 v = make_uint4(__float_as_uint(u[qi][0]), __float_as_uint(u[qi][1]),
                             __float_as_uint(u[qi][2]), __float_as_uint(u[qi][3]));
        *(uint4*)&rd[ql][split * 4] = v;
    }
    __syncthreads();

    // ---- phase 2: one wave merges 64 candidates -> top-8 -> fp64 refine ----
    if (tid < QPB) {
        const int ql = tid;
        float m[8];
        #pragma unroll
        for (int c = 0; c < 8; ++c) m[c] = FLT_MAX;
        #pragma unroll 4
        for (int i = 0; i < SPLITS; ++i) {
            uint4 v = *(const uint4*)&rd[ql][i * 4];
            unsigned vv[4] = { v.x, v.y, v.z, v.w };
            #pragma unroll
            for (int c = 0; c < 4; ++c) {
                float p = __uint_as_float(vv[c]);
                m[7] = fmed3(p, m[6], m[7]);
                m[6] = fmed3(p, m[5], m[6]);
                m[5] = fmed3(p, m[4], m[5]);
                m[4] = fmed3(p, m[3], m[4]);
                m[3] = fmed3(p, m[2], m[3]);
                m[2] = fmed3(p, m[1], m[2]);
                m[1] = fmed3(p, m[0], m[1]);
                m[0] = fminf(m[0], p);
            }
        }
        // exact fp64 refine of the 8 survivors (diff form: exact for fp32 in)
        int q = qbase + ql;
        double qx = (double)xyz_q[(b * NQ + q) * 3 + 0];
        double qy = (double)xyz_q[(b * NQ + q) * 3 + 1];
        double qz = (double)xyz_q[(b * NQ + q) * 3 + 2];
        double M0 = DBL_MAX, M1 = DBL_MAX, M2 = DBL_MAX;
        #pragma unroll
        for (int c = 0; c < 8; ++c) {
            unsigned ki = __float_as_uint(m[c]) & 0x7FFu;
            float4 ka = ks[(ki >> 7) * KROW + (ki & (KPS - 1))];
            double dx = qx - (double)ka.x;
            double dy = qy - (double)ka.y;
            double dz = qz - (double)ka.z;
            double dd = dx * dx + dy * dy + dz * dz;
            double x = __longlong_as_double(
                (long long)((((unsigned long long)__double_as_longlong(dd)) & ~0x7FFull)
                            | (unsigned long long)ki));
            double a1 = fmax(x, M1), a0 = fmax(x, M0);
            M2 = fmin(M2, a1);
            M1 = fmin(M1, a0);
            M0 = fmin(M0, x);
        }
        unsigned long long b0 = (unsigned long long)__double_as_longlong(M0);
        unsigned long long b1 = (unsigned long long)__double_as_longlong(M1);
        unsigned long long b2 = (unsigned long long)__double_as_longlong(M2);
        double e0 = __longlong_as_double((long long)(b0 & ~0x7FFull));
        double e1 = __longlong_as_double((long long)(b1 & ~0x7FFull));
        double e2 = __longlong_as_double((long long)(b2 & ~0x7FFull));
        e0 = fmax(e0, 1e-10);
        e1 = fmax(e1, 1e-10);
        e2 = fmax(e2, 1e-10);
        double w0 = 1.0 / e0, w1 = 1.0 / e1, w2 = 1.0 / e2;
        double s  = w0 + w1 + w2;
        int qg = b * NQ + q;
        wsw[qg] = make_float4((float)(w0 / s), (float)(w1 / s), (float)(w2 / s), 0.0f);
        wsi[qg] = make_int4((int)(b0 & 0x7FFull), (int)(b1 & 0x7FFull),
                            (int)(b2 & 0x7FFull), 0);
    }
}

// ---------------------------------------------------------------------------
// Kernel B: gather + weighted sum. One float4 output element per thread;
// 4096 blocks (32K waves) of pure memory work — TLP hides the cold-vk
// latency that fp_main's 8-wave/CU phase 3 could not.
// ---------------------------------------------------------------------------
__global__ __launch_bounds__(256) void fp_gather(
    const float4* __restrict__ vk,
    const float4* __restrict__ wsw,
    const int4*   __restrict__ wsi,
    float4*       __restrict__ out)
{
    int o  = blockIdx.x * 256 + threadIdx.x;   // 0 .. BB*NQ*C4-1
    int q  = o >> 5;                           // global query = b*NQ + n
    int c4 = o & (C4 - 1);
    int b  = q >> 13;                          // NQ = 8192

    float4 w = wsw[q];                         // 32 threads share (L1/L2 broadcast)
    int4   j = wsi[q];
    const float4* vb = vk + (size_t)b * NK * C4;
    float4 v0 = vb[j.x * C4 + c4];
    float4 v1 = vb[j.y * C4 + c4];
    float4 v2 = vb[j.z * C4 + c4];
    float4 res;
    res.x = fmaf(w.x, v0.x, fmaf(w.y, v1.x, w.z * v2.x));
    res.y = fmaf(w.x, v0.y, fmaf(w.y, v1.y, w.z * v2.y));
    res.z = fmaf(w.x, v0.z, fmaf(w.y, v1.z, w.z * v2.z));
    res.w = fmaf(w.x, v0.w, fmaf(w.y, v1.w, w.z * v2.w));
    out[o] = res;
}

// ---------------------------------------------------------------------------
extern "C" void kernel_launch(void* const* d_in, const int* in_sizes, int n_in,
                              void* d_out, int out_size, void* d_ws, size_t ws_size,
                              hipStream_t stream)
{
    const float* xyz_q = (const float*)d_in[0];
    const float* xyz_k = (const float*)d_in[1];
    const float* v_k   = (const float*)d_in[2];

    char* ws = (char*)d_ws;
    float4* wsw = (float4*)ws;                  // 512 KiB
    int4*   wsi = (int4*)(ws + (1u << 20));     // 512 KiB at +1 MiB

    fp_knn<<<dim3(NQ / QPB, BB), dim3(NTHR), 0, stream>>>(xyz_q, xyz_k, wsw, wsi);
    fp_gather<<<dim3(BB * NQ * C4 / 256), dim3(256), 0, stream>>>(
        (const float4*)v_k, wsw, wsi, (float4*)d_out);
}